// Round 10
// baseline (288.978 us; speedup 1.0000x reference)
//
#include <hip/hip_runtime.h>

// Round 10: R7 base + pair/ext fusion. Every y contributor (pair tile stores
// AND cross-parent ext entries) uses atomicAdd with old-value telescoped BN
// stats (dsum=d, dsq=d*(2*old+d) — exact under any interleaving), so ext
// blocks run concurrently with pair GEMM blocks in ONE kernel. 6 dispatches.

typedef short bf16x4 __attribute__((ext_vector_type(4)));
typedef short bf16x8 __attribute__((ext_vector_type(8)));
typedef float f32x16 __attribute__((ext_vector_type(16)));

__device__ __forceinline__ short f2bf(float f) {
    unsigned u = __float_as_uint(f);
    u += 0x7fffu + ((u >> 16) & 1u);
    return (short)(u >> 16);
}
__device__ __forceinline__ float bf2f(short s) {
    return __uint_as_float(((unsigned)(unsigned short)s) << 16);
}

// ---------------- fused setup: pack, geometry, ext scan, zero y1/y2 ----------
__global__ __launch_bounds__(256) void k_setup(
    const float* __restrict__ w_up, const float* __restrict__ w1,
    const float* __restrict__ w2, const float* __restrict__ f1,
    const int* __restrict__ nbr, const int* __restrict__ up_kidx,
    short* __restrict__ wupp, short* __restrict__ w1p,
    short* __restrict__ w2p, short* __restrict__ f1bf,
    int* __restrict__ pmask, int* __restrict__ perm_rows,
    int* __restrict__ rank, int* __restrict__ cnt,
    int2* __restrict__ ext, int* __restrict__ extc,
    float* __restrict__ y1, float* __restrict__ y2,
    int n1, int n2, int nbExt, int nbGeom)
{
    int tid = threadIdx.x;
    int bid = blockIdx.x;
    if (bid < nbExt) {
        long long tot = (long long)n2 * 16;          // float4 units
        long long gs = (long long)nbExt * 256;
        for (long long e = (long long)bid * 256 + tid; e < tot; e += gs) {
            ((float4*)y1)[e] = make_float4(0.f, 0.f, 0.f, 0.f);
            ((float4*)y2)[e] = make_float4(0.f, 0.f, 0.f, 0.f);
        }
        int i = bid * 256 + tid;
        unsigned hm = 0;
        if (i < n2) {
            #pragma unroll
            for (int t = 0; t < 27; ++t) {
                int s = nbr[(size_t)t * n2 + i];
                if (s < n2 && (s >> 2) != (i >> 2)) hm |= 1u << t;
            }
        }
        __shared__ int lcnt, lbase;
        if (tid == 0) lcnt = 0;
        __syncthreads();
        int nh = __popc(hm);
        int myofs = 0;
        if (nh) myofs = atomicAdd(&lcnt, nh);
        __syncthreads();
        if (tid == 0 && lcnt) lbase = atomicAdd(extc, lcnt);
        __syncthreads();
        if (nh) {
            int pos = lbase + myofs;
            unsigned m = hm;
            while (m) {
                int t = __ffs(m) - 1;
                m &= m - 1;
                int s = nbr[(size_t)t * n2 + i];
                ext[pos++] = make_int2(i, s | (t << 16));
            }
        }
    } else if (bid < nbExt + nbGeom) {
        int p = (bid - nbExt) * 256 + tid;
        if (p >= n1) return;
        int4 kd = *(const int4*)(up_kidx + 4 * p);
        int a = kd.x * 4 + 0, b = kd.y * 4 + 1, c = kd.z * 4 + 2, d = kd.w * 4 + 3;
        int t;
        if (a > b) { t = a; a = b; b = t; }
        if (c > d) { t = c; c = d; d = t; }
        if (a > c) { t = a; a = c; c = t; }
        if (b > d) { t = b; b = d; d = t; }
        if (b > c) { t = b; b = c; c = t; }
        perm_rows[4 * p + 0] = 4 * p + (a & 3);
        perm_rows[4 * p + 1] = 4 * p + (b & 3);
        perm_rows[4 * p + 2] = 4 * p + (c & 3);
        perm_rows[4 * p + 3] = 4 * p + (d & 3);
        int mask = (1 << (a >> 2)) | (1 << (b >> 2)) | (1 << (c >> 2)) | (1 << (d >> 2));
        pmask[p] = mask;
        rank[p] = atomicAdd(&cnt[mask], 1);
    } else {
        const long long nup = 65536, nw1 = 221184, nw2 = 110592;
        long long nf1 = (long long)n1 * 128;
        long long total = nup + nw1 + nw2 + nf1;
        long long gs = (long long)(gridDim.x - nbExt - nbGeom) * 256;
        for (long long e0 = (long long)(bid - nbExt - nbGeom) * 256 + tid;
             e0 < total; e0 += gs) {
            long long e = e0;
            if (e < nup) {           // Wcat[128][512] -> [ks8][nt16][64][8]
                int j = e & 7, l = (e >> 3) & 63, nt = (e >> 9) & 15, ks = (int)(e >> 13);
                int k = ks * 16 + (l >> 5) * 8 + j;
                int col = nt * 32 + (l & 31);
                wupp[e] = f2bf(w_up[((size_t)(col >> 6) * 128 + k) * 64 + (col & 63)]);
            } else if ((e -= nup) < nw1) {   // [27][8][2][64][8]
                int j = e & 7, l = (e >> 3) & 63, ch = (e >> 9) & 1, ks = (e >> 10) & 7, t = (int)(e >> 13);
                int k = ks * 16 + (l >> 5) * 8 + j;
                int col = ch * 32 + (l & 31);
                w1p[e] = f2bf(w1[((size_t)t * 128 + k) * 64 + col]);
            } else if ((e -= nw1) < nw2) {   // [27][4][2][64][8]
                int j = e & 7, l = (e >> 3) & 63, ch = (e >> 9) & 1, ks = (e >> 10) & 3, t = (int)(e >> 12);
                int k = ks * 16 + (l >> 5) * 8 + j;
                int col = ch * 32 + (l & 31);
                w2p[e] = f2bf(w2[((size_t)t * 64 + k) * 64 + col]);
            } else {
                e -= nw2;
                f1bf[e] = f2bf(f1[e]);
            }
        }
    }
}

// ------- dense up-GEMM + fused masked BN stats; block 0 = scan/tiles/perm ----
__global__ __launch_bounds__(256) void k_up(
    const short* __restrict__ f1bf, const short* __restrict__ wupp,
    const int* __restrict__ pmask, const int* __restrict__ cnt,
    const int* __restrict__ rank, int* __restrict__ perm_par,
    int4* __restrict__ tiles, int* __restrict__ ntl,
    short* __restrict__ yup8, float* __restrict__ stats, int n1)
{
    if (blockIdx.x == 0) {
        __shared__ int sA[256], sB[256], bb[256];
        int t = threadIdx.x;
        int c = cnt[t], tc = (c + 31) >> 5;
        sA[t] = c; sB[t] = tc;
        __syncthreads();
        for (int off = 1; off < 256; off <<= 1) {
            int a = (t >= off) ? sA[t - off] : 0;
            int b = (t >= off) ? sB[t - off] : 0;
            __syncthreads();
            sA[t] += a; sB[t] += b;
            __syncthreads();
        }
        int base = sA[t] - c, toff = sB[t] - tc;
        bb[t] = base;
        for (int j = 0; j < tc; ++j) tiles[toff + j] = make_int4(t, base, j * 32, c);
        if (t == 255) ntl[0] = sB[255];
        __syncthreads();
        for (int p = t; p < n1; p += 256)
            perm_par[bb[pmask[p]] + rank[p]] = p;
        return;
    }
    __shared__ short lds[32 * 136];                  // stride ≡ 4 mod 32 words
    __shared__ float bs[64], bq[64];
    int bid = blockIdx.x - 1;
    int tile = bid >> 1;
    int w = threadIdx.x >> 6, lane = threadIdx.x & 63;
    int na = (bid & 1) * 8 + w, nb = na + 4;
    if (threadIdx.x < 64) { bs[threadIdx.x] = 0.f; bq[threadIdx.x] = 0.f; }
    #pragma unroll
    for (int it = 0; it < 2; ++it) {
        int c = it * 256 + threadIdx.x;
        int row = c >> 4, col8 = c & 15;
        int gr = tile * 32 + row; if (gr >= n1) gr = n1 - 1;
        int4 g = *(const int4*)(f1bf + (size_t)gr * 128 + col8 * 8);
        short* d = &lds[row * 136 + col8 * 8];
        *(int2*)d = make_int2(g.x, g.y);
        *(int2*)(d + 4) = make_int2(g.z, g.w);
    }
    int m = lane & 31, half = lane >> 5;
    int pm_l = (tile * 32 + m < n1) ? pmask[tile * 32 + m] : 0;
    __syncthreads();
    f32x16 a0, a1;
    #pragma unroll
    for (int i = 0; i < 16; ++i) { a0[i] = 0.f; a1[i] = 0.f; }
    const bf16x8* bp = (const bf16x8*)wupp;
    #pragma unroll
    for (int ks = 0; ks < 8; ++ks) {
        const short* ap = &lds[m * 136 + ks * 16 + half * 8];
        bf16x4 lo = *(const bf16x4*)ap, hi = *(const bf16x4*)(ap + 4);
        bf16x8 a = __builtin_shufflevector(lo, hi, 0, 1, 2, 3, 4, 5, 6, 7);
        bf16x8 b0 = bp[(size_t)(ks * 16 + na) * 64 + lane];
        bf16x8 b1 = bp[(size_t)(ks * 16 + nb) * 64 + lane];
        a0 = __builtin_amdgcn_mfma_f32_32x32x16_bf16(a, b0, a0, 0, 0, 0);
        a1 = __builtin_amdgcn_mfma_f32_32x32x16_bf16(a, b1, a1, 0, 0, 0);
    }
    int col = lane & 31;
    #pragma unroll
    for (int pass = 0; pass < 2; ++pass) {
        const f32x16& acc = pass ? a1 : a0;
        int n = pass ? nb : na;
        int slot = n >> 1, c = (n & 1) * 32 + col;
        float s0 = 0.f, q0 = 0.f;
        #pragma unroll
        for (int reg = 0; reg < 16; ++reg) {
            int r = (reg & 3) + 8 * (reg >> 2) + 4 * half;
            int p = tile * 32 + r;
            float v = acc[reg];
            int mk = __shfl(pm_l, r);
            if (p < n1) {
                yup8[(size_t)p * 512 + n * 32 + col] = f2bf(v);
                if ((mk >> slot) & 1) { s0 += v; q0 += v * v; }
            }
        }
        s0 += __shfl_xor(s0, 32);
        q0 += __shfl_xor(q0, 32);
        if (lane < 32) { atomicAdd(&bs[c], s0); atomicAdd(&bq[c], q0); }
    }
    __syncthreads();
    if (threadIdx.x < 64) {
        atomicAdd(&stats[threadIdx.x], bs[threadIdx.x]);
        atomicAdd(&stats[64 + threadIdx.x], bq[threadIdx.x]);
    }
}

// --- epilogue: atomicAdd all 32 (two-phase), telescoped BN stats -------------
__device__ __forceinline__ void pair_epi_at(const f32x16& a0v, const f32x16& a1v,
                                            int outrow0, int outrow1, int lane,
                                            int ch, float* __restrict__ y,
                                            float* __restrict__ bs,
                                            float* __restrict__ bq)
{
    int col = lane & 31;
    int c = ch * 32 + col;
    int r0[16], r1[16];
    #pragma unroll
    for (int reg = 0; reg < 16; ++reg) {
        int r = (reg & 3) + 8 * (reg >> 2) + 4 * (lane >> 5);
        r0[reg] = __shfl(outrow0, r);
        r1[reg] = __shfl(outrow1, r);
    }
    float o0[16], o1[16];
    #pragma unroll
    for (int reg = 0; reg < 16; ++reg) {      // issue all atomics before use
        o0[reg] = (r0[reg] >= 0) ? atomicAdd(&y[(size_t)r0[reg] * 64 + c], a0v[reg]) : 0.f;
        o1[reg] = (r1[reg] >= 0) ? atomicAdd(&y[(size_t)r1[reg] * 64 + c], a1v[reg]) : 0.f;
    }
    float s0 = 0.f, q0 = 0.f;
    #pragma unroll
    for (int reg = 0; reg < 16; ++reg) {
        if (r0[reg] >= 0) { float d = a0v[reg]; s0 += d; q0 += d * (2.f * o0[reg] + d); }
        if (r1[reg] >= 0) { float d = a1v[reg]; s0 += d; q0 += d * (2.f * o1[reg] + d); }
    }
    s0 += __shfl_xor(s0, 32);
    q0 += __shfl_xor(q0, 32);
    if (lane < 32) { atomicAdd(&bs[c], s0); atomicAdd(&bq[c], q0); }
}

__device__ __forceinline__ int tap27(int pa, int pb) {
    int di = ((pb >> 2) & 1) - ((pa >> 2) & 1);
    int dj = ((pb >> 1) & 1) - ((pa >> 1) & 1);
    int dk = (pb & 1) - (pa & 1);
    return (di + 1) * 9 + (dj + 1) * 3 + (dk + 1);
}

// conv1 fused: blocks [0,maxTiles) = pattern GEMM; [maxTiles,+NE) = ext entries
__global__ __launch_bounds__(256) void k_convA(
    const short* __restrict__ yup8, const float* __restrict__ f2,
    const int* __restrict__ up_kidx, const short* __restrict__ wp,
    const float* __restrict__ w1f,
    const float* __restrict__ gamma, const float* __restrict__ beta,
    const float* __restrict__ stats, const int* __restrict__ perm_par,
    const int* __restrict__ perm_rows, const int4* __restrict__ tiles,
    const int* __restrict__ n_tiles, const int2* __restrict__ ext,
    const int* __restrict__ extc, float* __restrict__ y,
    float* __restrict__ ostats, int n2, int maxT)
{
    constexpr int LP = 520;                   // 260 words ≡ 4 mod 32: b128-clean
    __shared__ short lds[32 * LP];
    __shared__ int srows[128], soff[128];
    __shared__ float scs[64], shs[64], bs[64], bq[64];
    int tid = threadIdx.x;
    if (blockIdx.x >= maxT) {
        // ---- ext path: y[i] += x[s]·w1[t], telescoped stats ----
        if (tid < 64) {
            float inv = 1.0f / (float)n2;
            float mean = stats[tid] * inv;
            float var = stats[64 + tid] * inv - mean * mean;
            float s = gamma[tid] * rsqrtf(var + 1e-5f);
            scs[tid] = s; shs[tid] = beta[tid] - mean * s;
            bs[tid] = 0.f; bq[tid] = 0.f;
        }
        __syncthreads();
        int gw = ((blockIdx.x - maxT) * 256 + tid) >> 6;
        int nw = ((gridDim.x - maxT) * 256) >> 6;
        int c = tid & 63;
        int ec = extc[0];
        float ls = 0.f, lq = 0.f;
        for (int e = gw; e < ec; e += nw) {
            int2 en = ext[e];
            int i = en.x, s = en.y & 0xFFFF, t = en.y >> 16;
            const short* xr = yup8 + (size_t)(s >> 2) * 512 + up_kidx[s] * 64;
            const float* fr = f2 + (size_t)s * 64;
            const float* wr = w1f + (size_t)t * 8192 + c;
            float acc = 0.f;
            #pragma unroll 4
            for (int k = 0; k < 64; ++k) {
                float xk = fmaxf(bf2f(xr[k]) * scs[k] + shs[k], 0.f);
                acc += xk * wr[(size_t)k * 64];
            }
            #pragma unroll 4
            for (int k = 0; k < 64; ++k)
                acc += fr[k] * wr[(size_t)(64 + k) * 64];
            float old = atomicAdd(&y[(size_t)i * 64 + c], acc);
            ls += acc;
            lq += acc * (2.f * old + acc);
        }
        atomicAdd(&bs[c], ls);
        atomicAdd(&bq[c], lq);
        __syncthreads();
        if (tid < 64) {
            atomicAdd(&ostats[tid], bs[tid]);
            atomicAdd(&ostats[64 + tid], bq[tid]);
        }
        return;
    }
    int bt = blockIdx.x;
    if (bt >= n_tiles[0]) return;
    int4 td = tiles[bt];
    int mask = td.x, p_start = td.y, lt = td.z, cntb = td.w;
    if (tid < 128) {
        int li = lt + (tid >> 2);
        int pid = perm_par[p_start + ((li < cntb) ? li : 0)];
        int i = perm_rows[pid * 4 + (tid & 3)];
        srows[tid] = i;
        soff[tid] = (i >> 2) * 512 + up_kidx[i] * 64;
    } else if (tid < 192) {
        int cc = tid - 128;
        float inv = 1.0f / (float)n2;
        float mean = stats[cc] * inv;
        float var = stats[64 + cc] * inv - mean * mean;
        float s = gamma[cc] * rsqrtf(var + 1e-5f);
        scs[cc] = s; shs[cc] = beta[cc] - mean * s;
    } else {
        int cc = tid - 192;
        bs[cc] = 0.f; bq[cc] = 0.f;
    }
    __syncthreads();
    #pragma unroll
    for (int it = 0; it < 8; ++it) {
        int c0 = it * 256 + tid;
        int pl = c0 >> 6, w8 = c0 & 63;
        int j = w8 >> 4, col8 = w8 & 15;
        short* d = &lds[pl * LP + j * 128 + col8 * 8];
        if (col8 < 8) {
            bf16x8 g = *(const bf16x8*)(yup8 + (size_t)soff[pl * 4 + j] + col8 * 8);
            short o[8];
            #pragma unroll
            for (int u = 0; u < 8; ++u) {
                int cc = col8 * 8 + u;
                o[u] = f2bf(fmaxf(bf2f(g[u]) * scs[cc] + shs[cc], 0.f));
            }
            *(int2*)d = make_int2(((int)(unsigned short)o[0]) | ((int)o[1] << 16),
                                  ((int)(unsigned short)o[2]) | ((int)o[3] << 16));
            *(int2*)(d + 4) = make_int2(((int)(unsigned short)o[4]) | ((int)o[5] << 16),
                                        ((int)(unsigned short)o[6]) | ((int)o[7] << 16));
        } else {
            const float* fr = f2 + (size_t)srows[pl * 4 + j] * 64 + (col8 - 8) * 8;
            float4 f0 = *(const float4*)fr;
            float4 f1v = *(const float4*)(fr + 4);
            short o[8] = {f2bf(f0.x), f2bf(f0.y), f2bf(f0.z), f2bf(f0.w),
                          f2bf(f1v.x), f2bf(f1v.y), f2bf(f1v.z), f2bf(f1v.w)};
            *(int2*)d = make_int2(((int)(unsigned short)o[0]) | ((int)o[1] << 16),
                                  ((int)(unsigned short)o[2]) | ((int)o[3] << 16));
            *(int2*)(d + 4) = make_int2(((int)(unsigned short)o[4]) | ((int)o[5] << 16),
                                        ((int)(unsigned short)o[6]) | ((int)o[7] << 16));
        }
    }
    int p0 = -1, p1 = -1, p2 = -1, p3 = -1;
    #pragma unroll
    for (int b = 7; b >= 0; --b)
        if ((mask >> b) & 1) { p3 = p2; p2 = p1; p1 = p0; p0 = b; }
    int w = tid >> 6, lane = tid & 63;
    int a0 = w >> 1, a1 = a0 + 2, ch = w & 1;
    int pa0 = (a0 == 0) ? p0 : p1;
    int pa1 = (a1 == 2) ? p2 : p3;
    int t00 = tap27(pa0, p0), t01 = tap27(pa0, p1), t02 = tap27(pa0, p2), t03 = tap27(pa0, p3);
    int t10 = tap27(pa1, p0), t11 = tap27(pa1, p1), t12 = tap27(pa1, p2), t13 = tap27(pa1, p3);
    int m = lane & 31, half = lane >> 5;
    int li = lt + m;
    bool vp = li < cntb;
    int pid = perm_par[p_start + (vp ? li : 0)];
    int outrow0 = vp ? perm_rows[pid * 4 + a0] : -1;
    int outrow1 = vp ? perm_rows[pid * 4 + a1] : -1;
    __syncthreads();
    f32x16 acc0, acc1;
    #pragma unroll
    for (int i = 0; i < 16; ++i) { acc0[i] = 0.f; acc1[i] = 0.f; }
    const bf16x8* bp = (const bf16x8*)wp;
    #pragma unroll
    for (int b = 0; b < 4; ++b) {
        int tb0 = (b == 0) ? t00 : (b == 1) ? t01 : (b == 2) ? t02 : t03;
        int tb1 = (b == 0) ? t10 : (b == 1) ? t11 : (b == 2) ? t12 : t13;
        #pragma unroll
        for (int kk = 0; kk < 8; ++kk) {
            int ks = b * 8 + kk;
            const short* ap = &lds[m * LP + ks * 16 + half * 8];
            bf16x4 lo = *(const bf16x4*)ap, hi = *(const bf16x4*)(ap + 4);
            bf16x8 a = __builtin_shufflevector(lo, hi, 0, 1, 2, 3, 4, 5, 6, 7);
            bf16x8 b0 = bp[((size_t)(tb0 * 8 + kk) * 2 + ch) * 64 + lane];
            bf16x8 b1 = bp[((size_t)(tb1 * 8 + kk) * 2 + ch) * 64 + lane];
            acc0 = __builtin_amdgcn_mfma_f32_32x32x16_bf16(a, b0, acc0, 0, 0, 0);
            acc1 = __builtin_amdgcn_mfma_f32_32x32x16_bf16(a, b1, acc1, 0, 0, 0);
        }
    }
    pair_epi_at(acc0, acc1, outrow0, outrow1, lane, ch, y, bs, bq);
    __syncthreads();
    if (tid < 64) {
        atomicAdd(&ostats[tid], bs[tid]);
        atomicAdd(&ostats[64 + tid], bq[tid]);
    }
}

// conv2 fused: CH=64, A-rows = bn_relu1(y1); ext blocks appended
__global__ __launch_bounds__(256) void k_convB(
    const float* __restrict__ y1, const short* __restrict__ wp,
    const float* __restrict__ w2f,
    const float* __restrict__ gamma, const float* __restrict__ beta,
    const float* __restrict__ stats, const int* __restrict__ perm_par,
    const int* __restrict__ perm_rows, const int4* __restrict__ tiles,
    const int* __restrict__ n_tiles, const int2* __restrict__ ext,
    const int* __restrict__ extc, float* __restrict__ y,
    float* __restrict__ ostats, int n2, int maxT)
{
    constexpr int LP = 264;                   // 132 words ≡ 4 mod 32
    __shared__ short lds[32 * LP];
    __shared__ int srows[128];
    __shared__ float scs[64], shs[64], bs[64], bq[64];
    int tid = threadIdx.x;
    if (blockIdx.x >= maxT) {
        // ---- ext path: y[i] += bn_relu1(y1[s])·w2[t], telescoped stats ----
        if (tid < 64) {
            float inv = 1.0f / (float)n2;
            float mean = stats[tid] * inv;
            float var = stats[64 + tid] * inv - mean * mean;
            float s = gamma[tid] * rsqrtf(var + 1e-5f);
            scs[tid] = s; shs[tid] = beta[tid] - mean * s;
            bs[tid] = 0.f; bq[tid] = 0.f;
        }
        __syncthreads();
        int gw = ((blockIdx.x - maxT) * 256 + tid) >> 6;
        int nw = ((gridDim.x - maxT) * 256) >> 6;
        int c = tid & 63;
        int ec = extc[0];
        float ls = 0.f, lq = 0.f;
        for (int e = gw; e < ec; e += nw) {
            int2 en = ext[e];
            int i = en.x, s = en.y & 0xFFFF, t = en.y >> 16;
            const float* hr = y1 + (size_t)s * 64;
            const float* wr = w2f + (size_t)t * 4096 + c;
            float acc = 0.f;
            #pragma unroll 4
            for (int k = 0; k < 64; ++k) {
                float hk = fmaxf(hr[k] * scs[k] + shs[k], 0.f);
                acc += hk * wr[(size_t)k * 64];
            }
            float old = atomicAdd(&y[(size_t)i * 64 + c], acc);
            ls += acc;
            lq += acc * (2.f * old + acc);
        }
        atomicAdd(&bs[c], ls);
        atomicAdd(&bq[c], lq);
        __syncthreads();
        if (tid < 64) {
            atomicAdd(&ostats[tid], bs[tid]);
            atomicAdd(&ostats[64 + tid], bq[tid]);
        }
        return;
    }
    int bt = blockIdx.x;
    if (bt >= n_tiles[0]) return;
    int4 td = tiles[bt];
    int mask = td.x, p_start = td.y, lt = td.z, cntb = td.w;
    if (tid < 128) {
        int li = lt + (tid >> 2);
        int pid = perm_par[p_start + ((li < cntb) ? li : 0)];
        srows[tid] = perm_rows[pid * 4 + (tid & 3)];
    } else if (tid < 192) {
        int cc = tid - 128;
        float inv = 1.0f / (float)n2;
        float mean = stats[cc] * inv;
        float var = stats[64 + cc] * inv - mean * mean;
        float s = gamma[cc] * rsqrtf(var + 1e-5f);
        scs[cc] = s; shs[cc] = beta[cc] - mean * s;
    } else {
        int cc = tid - 192;
        bs[cc] = 0.f; bq[cc] = 0.f;
    }
    __syncthreads();
    #pragma unroll
    for (int it = 0; it < 4; ++it) {
        int c0 = it * 256 + tid;
        int pl = c0 >> 5, w8 = c0 & 31;
        int j = w8 >> 3, col8 = w8 & 7;
        const float* fr = y1 + (size_t)srows[pl * 4 + j] * 64 + col8 * 8;
        float4 f0 = *(const float4*)fr;
        float4 f1v = *(const float4*)(fr + 4);
        short o[8];
        #pragma unroll
        for (int u = 0; u < 4; ++u) {
            int cc = col8 * 8 + u;
            float v = (u == 0) ? f0.x : (u == 1) ? f0.y : (u == 2) ? f0.z : f0.w;
            o[u] = f2bf(fmaxf(v * scs[cc] + shs[cc], 0.f));
        }
        #pragma unroll
        for (int u = 0; u < 4; ++u) {
            int cc = col8 * 8 + 4 + u;
            float v = (u == 0) ? f1v.x : (u == 1) ? f1v.y : (u == 2) ? f1v.z : f1v.w;
            o[4 + u] = f2bf(fmaxf(v * scs[cc] + shs[cc], 0.f));
        }
        short* d = &lds[pl * LP + j * 64 + col8 * 8];
        *(int2*)d = make_int2(((int)(unsigned short)o[0]) | ((int)o[1] << 16),
                              ((int)(unsigned short)o[2]) | ((int)o[3] << 16));
        *(int2*)(d + 4) = make_int2(((int)(unsigned short)o[4]) | ((int)o[5] << 16),
                                    ((int)(unsigned short)o[6]) | ((int)o[7] << 16));
    }
    int p0 = -1, p1 = -1, p2 = -1, p3 = -1;
    #pragma unroll
    for (int b = 7; b >= 0; --b)
        if ((mask >> b) & 1) { p3 = p2; p2 = p1; p1 = p0; p0 = b; }
    int w = tid >> 6, lane = tid & 63;
    int a0 = w >> 1, a1 = a0 + 2, ch = w & 1;
    int pa0 = (a0 == 0) ? p0 : p1;
    int pa1 = (a1 == 2) ? p2 : p3;
    int t00 = tap27(pa0, p0), t01 = tap27(pa0, p1), t02 = tap27(pa0, p2), t03 = tap27(pa0, p3);
    int t10 = tap27(pa1, p0), t11 = tap27(pa1, p1), t12 = tap27(pa1, p2), t13 = tap27(pa1, p3);
    int m = lane & 31, half = lane >> 5;
    int li = lt + m;
    bool vp = li < cntb;
    int pid = perm_par[p_start + (vp ? li : 0)];
    int outrow0 = vp ? perm_rows[pid * 4 + a0] : -1;
    int outrow1 = vp ? perm_rows[pid * 4 + a1] : -1;
    __syncthreads();
    f32x16 acc0, acc1;
    #pragma unroll
    for (int i = 0; i < 16; ++i) { acc0[i] = 0.f; acc1[i] = 0.f; }
    const bf16x8* bp = (const bf16x8*)wp;
    #pragma unroll
    for (int b = 0; b < 4; ++b) {
        int tb0 = (b == 0) ? t00 : (b == 1) ? t01 : (b == 2) ? t02 : t03;
        int tb1 = (b == 0) ? t10 : (b == 1) ? t11 : (b == 2) ? t12 : t13;
        #pragma unroll
        for (int kk = 0; kk < 4; ++kk) {
            int ks = b * 4 + kk;
            const short* ap = &lds[m * LP + ks * 16 + half * 8];
            bf16x4 lo = *(const bf16x4*)ap, hi = *(const bf16x4*)(ap + 4);
            bf16x8 a = __builtin_shufflevector(lo, hi, 0, 1, 2, 3, 4, 5, 6, 7);
            bf16x8 b0 = bp[((size_t)(tb0 * 4 + kk) * 2 + ch) * 64 + lane];
            bf16x8 b1 = bp[((size_t)(tb1 * 4 + kk) * 2 + ch) * 64 + lane];
            acc0 = __builtin_amdgcn_mfma_f32_32x32x16_bf16(a, b0, acc0, 0, 0, 0);
            acc1 = __builtin_amdgcn_mfma_f32_32x32x16_bf16(a, b1, acc1, 0, 0, 0);
        }
    }
    pair_epi_at(acc0, acc1, outrow0, outrow1, lane, ch, y, bs, bq);
    __syncthreads();
    if (tid < 64) {
        atomicAdd(&ostats[tid], bs[tid]);
        atomicAdd(&ostats[64 + tid], bq[tid]);
    }
}

// ---------------- BN finalize + ReLU -> f32 output ---------------------------
__global__ __launch_bounds__(256) void k_final(
    const float* __restrict__ y, const float* __restrict__ gamma,
    const float* __restrict__ beta, const float* __restrict__ stats,
    float* __restrict__ out, int n2)
{
    __shared__ float sc[64], sh[64];
    int tid = threadIdx.x;
    if (tid < 64) {
        float inv = 1.0f / (float)n2;
        float mean = stats[tid] * inv;
        float var = stats[64 + tid] * inv - mean * mean;
        float s = gamma[tid] * rsqrtf(var + 1e-5f);
        sc[tid] = s;
        sh[tid] = beta[tid] - mean * s;
    }
    __syncthreads();
    long long total = (long long)n2 * 16;
    long long stride = (long long)gridDim.x * blockDim.x;
    for (long long idx = (long long)blockIdx.x * blockDim.x + tid; idx < total; idx += stride) {
        int i = (int)(idx >> 4);
        int c4 = ((int)idx & 15) * 4;
        const float* src = y + (size_t)i * 64 + c4;
        float4 o;
        o.x = fmaxf(src[0] * sc[c4 + 0] + sh[c4 + 0], 0.f);
        o.y = fmaxf(src[1] * sc[c4 + 1] + sh[c4 + 1], 0.f);
        o.z = fmaxf(src[2] * sc[c4 + 2] + sh[c4 + 2], 0.f);
        o.w = fmaxf(src[3] * sc[c4 + 3] + sh[c4 + 3], 0.f);
        *(float4*)(out + (size_t)i * 64 + c4) = o;
    }
}

extern "C" void kernel_launch(void* const* d_in, const int* in_sizes, int n_in,
                              void* d_out, int out_size, void* d_ws, size_t ws_size,
                              hipStream_t stream)
{
    const float* feats1   = (const float*)d_in[0];
    const float* feats2   = (const float*)d_in[1];
    const float* w_up     = (const float*)d_in[2];
    const float* gamma_up = (const float*)d_in[3];
    const float* beta_up  = (const float*)d_in[4];
    const float* w1       = (const float*)d_in[5];
    const float* gamma1   = (const float*)d_in[6];
    const float* beta1    = (const float*)d_in[7];
    const float* w2       = (const float*)d_in[8];
    const float* gamma2   = (const float*)d_in[9];
    const float* beta2    = (const float*)d_in[10];
    const int* up_kidx    = (const int*)d_in[12];
    const int* nbr_src    = (const int*)d_in[13];
    // d_in[11] up_src, d_in[14] nbr_dst unused (structure known)

    int n1 = in_sizes[0] / 128;
    int n2 = in_sizes[1] / 64;

    char* p = (char*)d_ws;
    auto alloc = [&](size_t bytes) {
        char* r = p;
        p += (bytes + 255) & ~(size_t)255;
        return r;
    };
    // head block (memset-zeroed): stats | cnt | extc | ntl
    float* stats    = (float*)alloc(384 * 4);
    int*   cnt      = (int*)alloc(256 * 4);
    int*   extc     = (int*)alloc(16);
    int*   ntl      = (int*)alloc(16);
    size_t headBytes = (size_t)(p - (char*)d_ws);
    int maxTiles    = (n1 + 31) / 32 + 80;
    int4*  tiles    = (int4*)alloc((size_t)maxTiles * 16);
    short* wupp     = (short*)alloc((size_t)65536 * 2);
    short* w1p      = (short*)alloc((size_t)221184 * 2);
    short* w2p      = (short*)alloc((size_t)110592 * 2);
    short* f1bf     = (short*)alloc((size_t)n1 * 128 * 2);
    int*   pmask    = (int*)alloc((size_t)n1 * 4);
    int*   rank     = (int*)alloc((size_t)n1 * 4);
    int*   perm_par = (int*)alloc((size_t)n1 * 4);
    int*   perm_rows= (int*)alloc((size_t)4 * n1 * 4);
    int2*  ext      = (int2*)alloc((size_t)27 * n2 * 8);
    short* yup8     = (short*)alloc((size_t)n1 * 512 * 2);
    float* y1       = (float*)alloc((size_t)n2 * 64 * 4);
    float* y2       = (float*)alloc((size_t)n2 * 64 * 4);

    int nbExt  = (n2 + 255) / 256;
    int nbGeom = (n1 + 255) / 256;
    int nbPack = 256;
    int nbSetup = nbExt + nbGeom + nbPack;
    int upBlocks = 1 + 2 * ((n1 + 31) / 32);
    int extBlk   = 128;
    int ewBlocks16 = (int)(((long long)n2 * 16 + 255) / 256);

    hipMemsetAsync(d_ws, 0, headBytes, stream);
    k_setup<<<nbSetup, 256, 0, stream>>>(w_up, w1, w2, feats1, nbr_src, up_kidx,
                                         wupp, w1p, w2p, f1bf, pmask, perm_rows,
                                         rank, cnt, ext, extc, y1, y2,
                                         n1, n2, nbExt, nbGeom);
    k_up<<<upBlocks, 256, 0, stream>>>(f1bf, wupp, pmask, cnt, rank, perm_par,
                                       tiles, ntl, yup8, stats, n1);
    k_convA<<<maxTiles + extBlk, 256, 0, stream>>>(
        yup8, feats2, up_kidx, w1p, w1, gamma_up, beta_up, stats, perm_par,
        perm_rows, tiles, ntl, ext, extc, y1, stats + 128, n2, maxTiles);
    k_convB<<<maxTiles + extBlk, 256, 0, stream>>>(
        y1, w2p, w2, gamma1, beta1, stats + 128, perm_par, perm_rows, tiles,
        ntl, ext, extc, y2, stats + 256, n2, maxTiles);
    k_final<<<ewBlocks16, 256, 0, stream>>>(y2, gamma2, beta2, stats + 256,
                                            (float*)d_out, n2);
}

// Round 11
// 249.554 us; speedup vs baseline: 1.1580x; 1.1580x over previous
//
#include <hip/hip_runtime.h>

// Round 11: exact revert to the Round-7 configuration (best measured 251.9us).
// R8 (yup4/ebit, +13us), R9 (ext-after-pair, +21us), R10 (atomic fusion,
// +37us) all regressed — R7 is the empirical optimum for this structure.
// (a) two-phase GEMM epilogue — all 32 scattered y-loads issued before any
// store; (b) LDS word-stride ≡ 4 (mod 32) for conflict-free ds_read_b128.

typedef short bf16x4 __attribute__((ext_vector_type(4)));
typedef short bf16x8 __attribute__((ext_vector_type(8)));
typedef float f32x16 __attribute__((ext_vector_type(16)));

__device__ __forceinline__ short f2bf(float f) {
    unsigned u = __float_as_uint(f);
    u += 0x7fffu + ((u >> 16) & 1u);
    return (short)(u >> 16);
}
__device__ __forceinline__ float bf2f(short s) {
    return __uint_as_float(((unsigned)(unsigned short)s) << 16);
}

// ---------------- fused setup: pack weights/feats, geometry, ext scan, zero --
__global__ __launch_bounds__(256) void k_setup(
    const float* __restrict__ w_up, const float* __restrict__ w1,
    const float* __restrict__ w2, const float* __restrict__ f1,
    const int* __restrict__ nbr, const int* __restrict__ up_kidx,
    short* __restrict__ wupp, short* __restrict__ w1p,
    short* __restrict__ w2p, short* __restrict__ f1bf,
    int* __restrict__ pmask, int* __restrict__ perm_rows,
    int* __restrict__ rank, int* __restrict__ cnt,
    int2* __restrict__ ext, int* __restrict__ extc,
    float* __restrict__ y1, float* __restrict__ y2,
    int n1, int n2, int nbExt, int nbGeom)
{
    int tid = threadIdx.x;
    int bid = blockIdx.x;
    if (bid < nbExt) {
        long long tot = (long long)n2 * 16;          // float4 units
        long long gs = (long long)nbExt * 256;
        for (long long e = (long long)bid * 256 + tid; e < tot; e += gs) {
            ((float4*)y1)[e] = make_float4(0.f, 0.f, 0.f, 0.f);
            ((float4*)y2)[e] = make_float4(0.f, 0.f, 0.f, 0.f);
        }
        int i = bid * 256 + tid;
        unsigned hm = 0;
        if (i < n2) {
            #pragma unroll
            for (int t = 0; t < 27; ++t) {
                int s = nbr[(size_t)t * n2 + i];
                if (s < n2 && (s >> 2) != (i >> 2)) hm |= 1u << t;
            }
        }
        __shared__ int lcnt, lbase;
        if (tid == 0) lcnt = 0;
        __syncthreads();
        int nh = __popc(hm);
        int myofs = 0;
        if (nh) myofs = atomicAdd(&lcnt, nh);
        __syncthreads();
        if (tid == 0 && lcnt) lbase = atomicAdd(extc, lcnt);
        __syncthreads();
        if (nh) {
            int pos = lbase + myofs;
            unsigned m = hm;
            while (m) {
                int t = __ffs(m) - 1;
                m &= m - 1;
                int s = nbr[(size_t)t * n2 + i];
                ext[pos++] = make_int2(i, s | (t << 16));
            }
        }
    } else if (bid < nbExt + nbGeom) {
        int p = (bid - nbExt) * 256 + tid;
        if (p >= n1) return;
        int4 kd = *(const int4*)(up_kidx + 4 * p);
        int a = kd.x * 4 + 0, b = kd.y * 4 + 1, c = kd.z * 4 + 2, d = kd.w * 4 + 3;
        int t;
        if (a > b) { t = a; a = b; b = t; }
        if (c > d) { t = c; c = d; d = t; }
        if (a > c) { t = a; a = c; c = t; }
        if (b > d) { t = b; b = d; d = t; }
        if (b > c) { t = b; b = c; c = t; }
        perm_rows[4 * p + 0] = 4 * p + (a & 3);
        perm_rows[4 * p + 1] = 4 * p + (b & 3);
        perm_rows[4 * p + 2] = 4 * p + (c & 3);
        perm_rows[4 * p + 3] = 4 * p + (d & 3);
        int mask = (1 << (a >> 2)) | (1 << (b >> 2)) | (1 << (c >> 2)) | (1 << (d >> 2));
        pmask[p] = mask;
        rank[p] = atomicAdd(&cnt[mask], 1);
    } else {
        const long long nup = 65536, nw1 = 221184, nw2 = 110592;
        long long nf1 = (long long)n1 * 128;
        long long total = nup + nw1 + nw2 + nf1;
        long long gs = (long long)(gridDim.x - nbExt - nbGeom) * 256;
        for (long long e0 = (long long)(bid - nbExt - nbGeom) * 256 + tid;
             e0 < total; e0 += gs) {
            long long e = e0;
            if (e < nup) {           // Wcat[128][512] -> [ks8][nt16][64][8]
                int j = e & 7, l = (e >> 3) & 63, nt = (e >> 9) & 15, ks = (int)(e >> 13);
                int k = ks * 16 + (l >> 5) * 8 + j;
                int col = nt * 32 + (l & 31);
                wupp[e] = f2bf(w_up[((size_t)(col >> 6) * 128 + k) * 64 + (col & 63)]);
            } else if ((e -= nup) < nw1) {   // [27][8][2][64][8]
                int j = e & 7, l = (e >> 3) & 63, ch = (e >> 9) & 1, ks = (e >> 10) & 7, t = (int)(e >> 13);
                int k = ks * 16 + (l >> 5) * 8 + j;
                int col = ch * 32 + (l & 31);
                w1p[e] = f2bf(w1[((size_t)t * 128 + k) * 64 + col]);
            } else if ((e -= nw1) < nw2) {   // [27][4][2][64][8]
                int j = e & 7, l = (e >> 3) & 63, ch = (e >> 9) & 1, ks = (e >> 10) & 3, t = (int)(e >> 12);
                int k = ks * 16 + (l >> 5) * 8 + j;
                int col = ch * 32 + (l & 31);
                w2p[e] = f2bf(w2[((size_t)t * 64 + k) * 64 + col]);
            } else {
                e -= nw2;
                f1bf[e] = f2bf(f1[e]);
            }
        }
    }
}

// ------- dense up-GEMM + fused masked BN stats; block 0 = scan/tiles/perm ----
__global__ __launch_bounds__(256) void k_up(
    const short* __restrict__ f1bf, const short* __restrict__ wupp,
    const int* __restrict__ pmask, const int* __restrict__ cnt,
    const int* __restrict__ rank, int* __restrict__ perm_par,
    int4* __restrict__ tiles, int* __restrict__ ntl,
    short* __restrict__ yup8, float* __restrict__ stats, int n1)
{
    if (blockIdx.x == 0) {
        __shared__ int sA[256], sB[256], bb[256];
        int t = threadIdx.x;
        int c = cnt[t], tc = (c + 31) >> 5;
        sA[t] = c; sB[t] = tc;
        __syncthreads();
        for (int off = 1; off < 256; off <<= 1) {
            int a = (t >= off) ? sA[t - off] : 0;
            int b = (t >= off) ? sB[t - off] : 0;
            __syncthreads();
            sA[t] += a; sB[t] += b;
            __syncthreads();
        }
        int base = sA[t] - c, toff = sB[t] - tc;
        bb[t] = base;
        for (int j = 0; j < tc; ++j) tiles[toff + j] = make_int4(t, base, j * 32, c);
        if (t == 255) ntl[0] = sB[255];
        __syncthreads();
        for (int p = t; p < n1; p += 256)
            perm_par[bb[pmask[p]] + rank[p]] = p;
        return;
    }
    __shared__ short lds[32 * 136];                  // stride 68 words ≡ 4 mod 32
    __shared__ float bs[64], bq[64];
    int bid = blockIdx.x - 1;
    int tile = bid >> 1;
    int w = threadIdx.x >> 6, lane = threadIdx.x & 63;
    int na = (bid & 1) * 8 + w, nb = na + 4;
    if (threadIdx.x < 64) { bs[threadIdx.x] = 0.f; bq[threadIdx.x] = 0.f; }
    #pragma unroll
    for (int it = 0; it < 2; ++it) {
        int c = it * 256 + threadIdx.x;
        int row = c >> 4, col8 = c & 15;
        int gr = tile * 32 + row; if (gr >= n1) gr = n1 - 1;
        int4 g = *(const int4*)(f1bf + (size_t)gr * 128 + col8 * 8);
        short* d = &lds[row * 136 + col8 * 8];
        *(int2*)d = make_int2(g.x, g.y);
        *(int2*)(d + 4) = make_int2(g.z, g.w);
    }
    int m = lane & 31, half = lane >> 5;
    int pm_l = (tile * 32 + m < n1) ? pmask[tile * 32 + m] : 0;
    __syncthreads();
    f32x16 a0, a1;
    #pragma unroll
    for (int i = 0; i < 16; ++i) { a0[i] = 0.f; a1[i] = 0.f; }
    const bf16x8* bp = (const bf16x8*)wupp;
    #pragma unroll
    for (int ks = 0; ks < 8; ++ks) {
        const short* ap = &lds[m * 136 + ks * 16 + half * 8];
        bf16x4 lo = *(const bf16x4*)ap, hi = *(const bf16x4*)(ap + 4);
        bf16x8 a = __builtin_shufflevector(lo, hi, 0, 1, 2, 3, 4, 5, 6, 7);
        bf16x8 b0 = bp[(size_t)(ks * 16 + na) * 64 + lane];
        bf16x8 b1 = bp[(size_t)(ks * 16 + nb) * 64 + lane];
        a0 = __builtin_amdgcn_mfma_f32_32x32x16_bf16(a, b0, a0, 0, 0, 0);
        a1 = __builtin_amdgcn_mfma_f32_32x32x16_bf16(a, b1, a1, 0, 0, 0);
    }
    int col = lane & 31;
    #pragma unroll
    for (int pass = 0; pass < 2; ++pass) {
        const f32x16& acc = pass ? a1 : a0;
        int n = pass ? nb : na;
        int slot = n >> 1, c = (n & 1) * 32 + col;
        float s0 = 0.f, q0 = 0.f;
        #pragma unroll
        for (int reg = 0; reg < 16; ++reg) {
            int r = (reg & 3) + 8 * (reg >> 2) + 4 * half;
            int p = tile * 32 + r;
            float v = acc[reg];
            int mk = __shfl(pm_l, r);
            if (p < n1) {
                yup8[(size_t)p * 512 + n * 32 + col] = f2bf(v);
                if ((mk >> slot) & 1) { s0 += v; q0 += v * v; }
            }
        }
        s0 += __shfl_xor(s0, 32);
        q0 += __shfl_xor(q0, 32);
        if (lane < 32) { atomicAdd(&bs[c], s0); atomicAdd(&bq[c], q0); }
    }
    __syncthreads();
    if (threadIdx.x < 64) {
        atomicAdd(&stats[threadIdx.x], bs[threadIdx.x]);
        atomicAdd(&stats[64 + threadIdx.x], bq[threadIdx.x]);
    }
}

// ---------------- ext kernels: on-the-fly BN input, atomicAdd into y ---------
__global__ __launch_bounds__(256) void k_extA(
    const short* __restrict__ yup8, const float* __restrict__ f2,
    const int* __restrict__ up_kidx, const float* __restrict__ w1,
    const float* __restrict__ gamma, const float* __restrict__ beta,
    const float* __restrict__ stats, const int2* __restrict__ ext,
    const int* __restrict__ extc, float* __restrict__ y, int n2)
{
    __shared__ float sc[64], sh[64];
    int tid = threadIdx.x;
    if (tid < 64) {
        float inv = 1.0f / (float)n2;
        float mean = stats[tid] * inv;
        float var = stats[64 + tid] * inv - mean * mean;
        float s = gamma[tid] * rsqrtf(var + 1e-5f);
        sc[tid] = s; sh[tid] = beta[tid] - mean * s;
    }
    __syncthreads();
    int gw = (blockIdx.x * 256 + tid) >> 6;
    int nw = (gridDim.x * 256) >> 6;
    int c = tid & 63;
    int ec = extc[0];
    for (int e = gw; e < ec; e += nw) {
        int2 en = ext[e];
        int i = en.x, s = en.y & 0xFFFF, t = en.y >> 16;
        const short* xr = yup8 + (size_t)(s >> 2) * 512 + up_kidx[s] * 64;
        const float* fr = f2 + (size_t)s * 64;
        const float* wr = w1 + (size_t)t * 8192 + c;
        float acc = 0.f;
        #pragma unroll 4
        for (int k = 0; k < 64; ++k) {
            float xk = fmaxf(bf2f(xr[k]) * sc[k] + sh[k], 0.f);
            acc += xk * wr[(size_t)k * 64];
        }
        #pragma unroll 4
        for (int k = 0; k < 64; ++k)
            acc += fr[k] * wr[(size_t)(64 + k) * 64];
        atomicAdd(&y[(size_t)i * 64 + c], acc);
    }
}

__global__ __launch_bounds__(256) void k_extB(
    const float* __restrict__ y1, const float* __restrict__ w2,
    const float* __restrict__ gamma, const float* __restrict__ beta,
    const float* __restrict__ stats, const int2* __restrict__ ext,
    const int* __restrict__ extc, float* __restrict__ y, int n2)
{
    __shared__ float sc[64], sh[64];
    int tid = threadIdx.x;
    if (tid < 64) {
        float inv = 1.0f / (float)n2;
        float mean = stats[tid] * inv;
        float var = stats[64 + tid] * inv - mean * mean;
        float s = gamma[tid] * rsqrtf(var + 1e-5f);
        sc[tid] = s; sh[tid] = beta[tid] - mean * s;
    }
    __syncthreads();
    int gw = (blockIdx.x * 256 + tid) >> 6;
    int nw = (gridDim.x * 256) >> 6;
    int c = tid & 63;
    int ec = extc[0];
    for (int e = gw; e < ec; e += nw) {
        int2 en = ext[e];
        int i = en.x, s = en.y & 0xFFFF, t = en.y >> 16;
        const float* hr = y1 + (size_t)s * 64;
        const float* wr = w2 + (size_t)t * 4096 + c;
        float acc = 0.f;
        #pragma unroll 4
        for (int k = 0; k < 64; ++k) {
            float hk = fmaxf(hr[k] * sc[k] + sh[k], 0.f);
            acc += hk * wr[(size_t)k * 64];
        }
        atomicAdd(&y[(size_t)i * 64 + c], acc);
    }
}

// ---- pattern-dense conv epilogue: two-phase (all loads, then all stores) ----
__device__ __forceinline__ void pair_epi2(const f32x16& a0v, const f32x16& a1v,
                                          int outrow0, int outrow1, int lane,
                                          int ch, float* __restrict__ y,
                                          float* __restrict__ bs,
                                          float* __restrict__ bq)
{
    int col = lane & 31;
    int c = ch * 32 + col;
    int r0[16], r1[16];
    #pragma unroll
    for (int reg = 0; reg < 16; ++reg) {
        int r = (reg & 3) + 8 * (reg >> 2) + 4 * (lane >> 5);
        r0[reg] = __shfl(outrow0, r);
        r1[reg] = __shfl(outrow1, r);
    }
    float o0[16], o1[16];
    #pragma unroll
    for (int reg = 0; reg < 16; ++reg) {      // unconditional clamped loads:
        int ra = (r0[reg] >= 0) ? r0[reg] : 0; // all 32 issued before any store
        int rb = (r1[reg] >= 0) ? r1[reg] : 0;
        o0[reg] = y[(size_t)ra * 64 + c];
        o1[reg] = y[(size_t)rb * 64 + c];
    }
    float s0 = 0.f, q0 = 0.f;
    #pragma unroll
    for (int reg = 0; reg < 16; ++reg) {
        if (r0[reg] >= 0) {
            float v = a0v[reg] + o0[reg];     // += externals pre-added by k_ext*
            y[(size_t)r0[reg] * 64 + c] = v;
            s0 += v; q0 += v * v;
        }
        if (r1[reg] >= 0) {
            float v = a1v[reg] + o1[reg];
            y[(size_t)r1[reg] * 64 + c] = v;
            s0 += v; q0 += v * v;
        }
    }
    s0 += __shfl_xor(s0, 32);
    q0 += __shfl_xor(q0, 32);
    if (lane < 32) { atomicAdd(&bs[c], s0); atomicAdd(&bq[c], q0); }
}

__device__ __forceinline__ int tap27(int pa, int pb) {
    int di = ((pb >> 2) & 1) - ((pa >> 2) & 1);
    int dj = ((pb >> 1) & 1) - ((pa >> 1) & 1);
    int dk = (pb & 1) - (pa & 1);
    return (di + 1) * 9 + (dj + 1) * 3 + (dk + 1);
}

// conv1: CH=128, A-rows built in staging: ch0-63 bn_relu(yup8), ch64-127 f2
__global__ __launch_bounds__(256) void k_pairA(
    const short* __restrict__ yup8, const float* __restrict__ f2,
    const int* __restrict__ up_kidx, const short* __restrict__ wp,
    const float* __restrict__ gamma, const float* __restrict__ beta,
    const float* __restrict__ stats, const int* __restrict__ perm_par,
    const int* __restrict__ perm_rows, const int4* __restrict__ tiles,
    const int* __restrict__ n_tiles, float* __restrict__ y,
    float* __restrict__ ostats, int n2)
{
    constexpr int LP = 520;                   // 260 words ≡ 4 mod 32: b128-clean
    __shared__ short lds[32 * LP];
    __shared__ int srows[128], soff[128];
    __shared__ float scs[64], shs[64], bs[64], bq[64];
    int bt = blockIdx.x;
    if (bt >= n_tiles[0]) return;
    int4 td = tiles[bt];
    int mask = td.x, p_start = td.y, lt = td.z, cntb = td.w;
    int tid = threadIdx.x;
    if (tid < 128) {
        int li = lt + (tid >> 2);
        int pid = perm_par[p_start + ((li < cntb) ? li : 0)];
        int i = perm_rows[pid * 4 + (tid & 3)];
        srows[tid] = i;
        soff[tid] = (i >> 2) * 512 + up_kidx[i] * 64;
    } else if (tid < 192) {
        int cc = tid - 128;
        float inv = 1.0f / (float)n2;
        float mean = stats[cc] * inv;
        float var = stats[64 + cc] * inv - mean * mean;
        float s = gamma[cc] * rsqrtf(var + 1e-5f);
        scs[cc] = s; shs[cc] = beta[cc] - mean * s;
    } else {
        int cc = tid - 192;
        bs[cc] = 0.f; bq[cc] = 0.f;
    }
    __syncthreads();
    #pragma unroll
    for (int it = 0; it < 8; ++it) {
        int c0 = it * 256 + tid;
        int pl = c0 >> 6, w8 = c0 & 63;
        int j = w8 >> 4, col8 = w8 & 15;
        short* d = &lds[pl * LP + j * 128 + col8 * 8];
        if (col8 < 8) {
            bf16x8 g = *(const bf16x8*)(yup8 + (size_t)soff[pl * 4 + j] + col8 * 8);
            short o[8];
            #pragma unroll
            for (int u = 0; u < 8; ++u) {
                int cc = col8 * 8 + u;
                o[u] = f2bf(fmaxf(bf2f(g[u]) * scs[cc] + shs[cc], 0.f));
            }
            *(int2*)d = make_int2(((int)(unsigned short)o[0]) | ((int)o[1] << 16),
                                  ((int)(unsigned short)o[2]) | ((int)o[3] << 16));
            *(int2*)(d + 4) = make_int2(((int)(unsigned short)o[4]) | ((int)o[5] << 16),
                                        ((int)(unsigned short)o[6]) | ((int)o[7] << 16));
        } else {
            const float* fr = f2 + (size_t)srows[pl * 4 + j] * 64 + (col8 - 8) * 8;
            float4 f0 = *(const float4*)fr;
            float4 f1v = *(const float4*)(fr + 4);
            short o[8] = {f2bf(f0.x), f2bf(f0.y), f2bf(f0.z), f2bf(f0.w),
                          f2bf(f1v.x), f2bf(f1v.y), f2bf(f1v.z), f2bf(f1v.w)};
            *(int2*)d = make_int2(((int)(unsigned short)o[0]) | ((int)o[1] << 16),
                                  ((int)(unsigned short)o[2]) | ((int)o[3] << 16));
            *(int2*)(d + 4) = make_int2(((int)(unsigned short)o[4]) | ((int)o[5] << 16),
                                        ((int)(unsigned short)o[6]) | ((int)o[7] << 16));
        }
    }
    int p0 = -1, p1 = -1, p2 = -1, p3 = -1;
    #pragma unroll
    for (int b = 7; b >= 0; --b)
        if ((mask >> b) & 1) { p3 = p2; p2 = p1; p1 = p0; p0 = b; }
    int w = tid >> 6, lane = tid & 63;
    int a0 = w >> 1, a1 = a0 + 2, ch = w & 1;
    int pa0 = (a0 == 0) ? p0 : p1;
    int pa1 = (a1 == 2) ? p2 : p3;
    int t00 = tap27(pa0, p0), t01 = tap27(pa0, p1), t02 = tap27(pa0, p2), t03 = tap27(pa0, p3);
    int t10 = tap27(pa1, p0), t11 = tap27(pa1, p1), t12 = tap27(pa1, p2), t13 = tap27(pa1, p3);
    int m = lane & 31, half = lane >> 5;
    int li = lt + m;
    bool vp = li < cntb;
    int pid = perm_par[p_start + (vp ? li : 0)];
    int outrow0 = vp ? perm_rows[pid * 4 + a0] : -1;
    int outrow1 = vp ? perm_rows[pid * 4 + a1] : -1;
    __syncthreads();
    f32x16 acc0, acc1;
    #pragma unroll
    for (int i = 0; i < 16; ++i) { acc0[i] = 0.f; acc1[i] = 0.f; }
    const bf16x8* bp = (const bf16x8*)wp;
    #pragma unroll
    for (int b = 0; b < 4; ++b) {
        int tb0 = (b == 0) ? t00 : (b == 1) ? t01 : (b == 2) ? t02 : t03;
        int tb1 = (b == 0) ? t10 : (b == 1) ? t11 : (b == 2) ? t12 : t13;
        #pragma unroll
        for (int kk = 0; kk < 8; ++kk) {
            int ks = b * 8 + kk;
            const short* ap = &lds[m * LP + ks * 16 + half * 8];
            bf16x4 lo = *(const bf16x4*)ap, hi = *(const bf16x4*)(ap + 4);
            bf16x8 a = __builtin_shufflevector(lo, hi, 0, 1, 2, 3, 4, 5, 6, 7);
            bf16x8 b0 = bp[((size_t)(tb0 * 8 + kk) * 2 + ch) * 64 + lane];
            bf16x8 b1 = bp[((size_t)(tb1 * 8 + kk) * 2 + ch) * 64 + lane];
            acc0 = __builtin_amdgcn_mfma_f32_32x32x16_bf16(a, b0, acc0, 0, 0, 0);
            acc1 = __builtin_amdgcn_mfma_f32_32x32x16_bf16(a, b1, acc1, 0, 0, 0);
        }
    }
    pair_epi2(acc0, acc1, outrow0, outrow1, lane, ch, y, bs, bq);
    __syncthreads();
    if (tid < 64) {
        atomicAdd(&ostats[tid], bs[tid]);
        atomicAdd(&ostats[64 + tid], bq[tid]);
    }
}

// conv2: CH=64, A-rows = bn_relu1(y1) staged f32->bf16
__global__ __launch_bounds__(256) void k_pairB(
    const float* __restrict__ y1, const short* __restrict__ wp,
    const float* __restrict__ gamma, const float* __restrict__ beta,
    const float* __restrict__ stats, const int* __restrict__ perm_par,
    const int* __restrict__ perm_rows, const int4* __restrict__ tiles,
    const int* __restrict__ n_tiles, float* __restrict__ y,
    float* __restrict__ ostats, int n2)
{
    constexpr int LP = 264;                   // 132 words ≡ 4 mod 32
    __shared__ short lds[32 * LP];
    __shared__ int srows[128];
    __shared__ float scs[64], shs[64], bs[64], bq[64];
    int bt = blockIdx.x;
    if (bt >= n_tiles[0]) return;
    int4 td = tiles[bt];
    int mask = td.x, p_start = td.y, lt = td.z, cntb = td.w;
    int tid = threadIdx.x;
    if (tid < 128) {
        int li = lt + (tid >> 2);
        int pid = perm_par[p_start + ((li < cntb) ? li : 0)];
        srows[tid] = perm_rows[pid * 4 + (tid & 3)];
    } else if (tid < 192) {
        int cc = tid - 128;
        float inv = 1.0f / (float)n2;
        float mean = stats[cc] * inv;
        float var = stats[64 + cc] * inv - mean * mean;
        float s = gamma[cc] * rsqrtf(var + 1e-5f);
        scs[cc] = s; shs[cc] = beta[cc] - mean * s;
    } else {
        int cc = tid - 192;
        bs[cc] = 0.f; bq[cc] = 0.f;
    }
    __syncthreads();
    #pragma unroll
    for (int it = 0; it < 4; ++it) {
        int c0 = it * 256 + tid;
        int pl = c0 >> 5, w8 = c0 & 31;
        int j = w8 >> 3, col8 = w8 & 7;
        const float* fr = y1 + (size_t)srows[pl * 4 + j] * 64 + col8 * 8;
        float4 f0 = *(const float4*)fr;
        float4 f1v = *(const float4*)(fr + 4);
        short o[8];
        #pragma unroll
        for (int u = 0; u < 4; ++u) {
            int cc = col8 * 8 + u;
            float v = (u == 0) ? f0.x : (u == 1) ? f0.y : (u == 2) ? f0.z : f0.w;
            o[u] = f2bf(fmaxf(v * scs[cc] + shs[cc], 0.f));
        }
        #pragma unroll
        for (int u = 0; u < 4; ++u) {
            int cc = col8 * 8 + 4 + u;
            float v = (u == 0) ? f1v.x : (u == 1) ? f1v.y : (u == 2) ? f1v.z : f1v.w;
            o[4 + u] = f2bf(fmaxf(v * scs[cc] + shs[cc], 0.f));
        }
        short* d = &lds[pl * LP + j * 64 + col8 * 8];
        *(int2*)d = make_int2(((int)(unsigned short)o[0]) | ((int)o[1] << 16),
                              ((int)(unsigned short)o[2]) | ((int)o[3] << 16));
        *(int2*)(d + 4) = make_int2(((int)(unsigned short)o[4]) | ((int)o[5] << 16),
                                    ((int)(unsigned short)o[6]) | ((int)o[7] << 16));
    }
    int p0 = -1, p1 = -1, p2 = -1, p3 = -1;
    #pragma unroll
    for (int b = 7; b >= 0; --b)
        if ((mask >> b) & 1) { p3 = p2; p2 = p1; p1 = p0; p0 = b; }
    int w = tid >> 6, lane = tid & 63;
    int a0 = w >> 1, a1 = a0 + 2, ch = w & 1;
    int pa0 = (a0 == 0) ? p0 : p1;
    int pa1 = (a1 == 2) ? p2 : p3;
    int t00 = tap27(pa0, p0), t01 = tap27(pa0, p1), t02 = tap27(pa0, p2), t03 = tap27(pa0, p3);
    int t10 = tap27(pa1, p0), t11 = tap27(pa1, p1), t12 = tap27(pa1, p2), t13 = tap27(pa1, p3);
    int m = lane & 31, half = lane >> 5;
    int li = lt + m;
    bool vp = li < cntb;
    int pid = perm_par[p_start + (vp ? li : 0)];
    int outrow0 = vp ? perm_rows[pid * 4 + a0] : -1;
    int outrow1 = vp ? perm_rows[pid * 4 + a1] : -1;
    __syncthreads();
    f32x16 acc0, acc1;
    #pragma unroll
    for (int i = 0; i < 16; ++i) { acc0[i] = 0.f; acc1[i] = 0.f; }
    const bf16x8* bp = (const bf16x8*)wp;
    #pragma unroll
    for (int b = 0; b < 4; ++b) {
        int tb0 = (b == 0) ? t00 : (b == 1) ? t01 : (b == 2) ? t02 : t03;
        int tb1 = (b == 0) ? t10 : (b == 1) ? t11 : (b == 2) ? t12 : t13;
        #pragma unroll
        for (int kk = 0; kk < 4; ++kk) {
            int ks = b * 4 + kk;
            const short* ap = &lds[m * LP + ks * 16 + half * 8];
            bf16x4 lo = *(const bf16x4*)ap, hi = *(const bf16x4*)(ap + 4);
            bf16x8 a = __builtin_shufflevector(lo, hi, 0, 1, 2, 3, 4, 5, 6, 7);
            bf16x8 b0 = bp[((size_t)(tb0 * 4 + kk) * 2 + ch) * 64 + lane];
            bf16x8 b1 = bp[((size_t)(tb1 * 4 + kk) * 2 + ch) * 64 + lane];
            acc0 = __builtin_amdgcn_mfma_f32_32x32x16_bf16(a, b0, acc0, 0, 0, 0);
            acc1 = __builtin_amdgcn_mfma_f32_32x32x16_bf16(a, b1, acc1, 0, 0, 0);
        }
    }
    pair_epi2(acc0, acc1, outrow0, outrow1, lane, ch, y, bs, bq);
    __syncthreads();
    if (tid < 64) {
        atomicAdd(&ostats[tid], bs[tid]);
        atomicAdd(&ostats[64 + tid], bq[tid]);
    }
}

// ---------------- BN finalize + ReLU -> f32 output ---------------------------
__global__ __launch_bounds__(256) void k_final(
    const float* __restrict__ y, const float* __restrict__ gamma,
    const float* __restrict__ beta, const float* __restrict__ stats,
    float* __restrict__ out, int n2)
{
    __shared__ float sc[64], sh[64];
    int tid = threadIdx.x;
    if (tid < 64) {
        float inv = 1.0f / (float)n2;
        float mean = stats[tid] * inv;
        float var = stats[64 + tid] * inv - mean * mean;
        float s = gamma[tid] * rsqrtf(var + 1e-5f);
        sc[tid] = s;
        sh[tid] = beta[tid] - mean * s;
    }
    __syncthreads();
    long long total = (long long)n2 * 16;
    long long stride = (long long)gridDim.x * blockDim.x;
    for (long long idx = (long long)blockIdx.x * blockDim.x + tid; idx < total; idx += stride) {
        int i = (int)(idx >> 4);
        int c4 = ((int)idx & 15) * 4;
        const float* src = y + (size_t)i * 64 + c4;
        float4 o;
        o.x = fmaxf(src[0] * sc[c4 + 0] + sh[c4 + 0], 0.f);
        o.y = fmaxf(src[1] * sc[c4 + 1] + sh[c4 + 1], 0.f);
        o.z = fmaxf(src[2] * sc[c4 + 2] + sh[c4 + 2], 0.f);
        o.w = fmaxf(src[3] * sc[c4 + 3] + sh[c4 + 3], 0.f);
        *(float4*)(out + (size_t)i * 64 + c4) = o;
    }
}

extern "C" void kernel_launch(void* const* d_in, const int* in_sizes, int n_in,
                              void* d_out, int out_size, void* d_ws, size_t ws_size,
                              hipStream_t stream)
{
    const float* feats1   = (const float*)d_in[0];
    const float* feats2   = (const float*)d_in[1];
    const float* w_up     = (const float*)d_in[2];
    const float* gamma_up = (const float*)d_in[3];
    const float* beta_up  = (const float*)d_in[4];
    const float* w1       = (const float*)d_in[5];
    const float* gamma1   = (const float*)d_in[6];
    const float* beta1    = (const float*)d_in[7];
    const float* w2       = (const float*)d_in[8];
    const float* gamma2   = (const float*)d_in[9];
    const float* beta2    = (const float*)d_in[10];
    const int* up_src     = (const int*)d_in[11];  (void)up_src;
    const int* up_kidx    = (const int*)d_in[12];
    const int* nbr_src    = (const int*)d_in[13];
    // d_in[14] nbr_dst unused: nbr_dst[t,i] ∈ {i, N2} by construction

    int n1 = in_sizes[0] / 128;
    int n2 = in_sizes[1] / 64;

    char* p = (char*)d_ws;
    auto alloc = [&](size_t bytes) {
        char* r = p;
        p += (bytes + 255) & ~(size_t)255;
        return r;
    };
    float* stats    = (float*)alloc(384 * 4);
    int*   cnt      = (int*)alloc(256 * 4);
    int*   extc     = (int*)alloc(16);
    int*   ntl      = (int*)alloc(16);
    size_t headBytes = (size_t)(p - (char*)d_ws);
    int maxTiles    = (n1 + 31) / 32 + 80;
    int4*  tiles    = (int4*)alloc((size_t)maxTiles * 16);
    short* wupp     = (short*)alloc((size_t)65536 * 2);
    short* w1p      = (short*)alloc((size_t)221184 * 2);
    short* w2p      = (short*)alloc((size_t)110592 * 2);
    short* f1bf     = (short*)alloc((size_t)n1 * 128 * 2);
    int*   pmask    = (int*)alloc((size_t)n1 * 4);
    int*   rank     = (int*)alloc((size_t)n1 * 4);
    int*   perm_par = (int*)alloc((size_t)n1 * 4);
    int*   perm_rows= (int*)alloc((size_t)4 * n1 * 4);
    int2*  ext      = (int2*)alloc((size_t)27 * n2 * 8);
    short* yup8     = (short*)alloc((size_t)n1 * 512 * 2);
    float* y1       = (float*)alloc((size_t)n2 * 64 * 4);
    float* y2       = (float*)alloc((size_t)n2 * 64 * 4);

    int nbExt  = (n2 + 255) / 256;
    int nbGeom = (n1 + 255) / 256;
    int nbPack = 256;
    int nbSetup = nbExt + nbGeom + nbPack;
    int upBlocks = 1 + 2 * ((n1 + 31) / 32);
    int ewBlocks16 = (int)(((long long)n2 * 16 + 255) / 256);

    hipMemsetAsync(d_ws, 0, headBytes, stream);
    k_setup<<<nbSetup, 256, 0, stream>>>(w_up, w1, w2, feats1, nbr_src, up_kidx,
                                         wupp, w1p, w2p, f1bf, pmask, perm_rows,
                                         rank, cnt, ext, extc, y1, y2,
                                         n1, n2, nbExt, nbGeom);
    k_up<<<upBlocks, 256, 0, stream>>>(f1bf, wupp, pmask, cnt, rank, perm_par,
                                       tiles, ntl, yup8, stats, n1);
    k_extA<<<512, 256, 0, stream>>>(yup8, feats2, up_kidx, w1, gamma_up, beta_up,
                                    stats, ext, extc, y1, n2);
    k_pairA<<<maxTiles, 256, 0, stream>>>(yup8, feats2, up_kidx, w1p, gamma_up,
                                          beta_up, stats, perm_par, perm_rows,
                                          tiles, ntl, y1, stats + 128, n2);
    k_extB<<<512, 256, 0, stream>>>(y1, w2, gamma1, beta1, stats + 128, ext,
                                    extc, y2, n2);
    k_pairB<<<maxTiles, 256, 0, stream>>>(y1, w2p, gamma1, beta1, stats + 128,
                                          perm_par, perm_rows, tiles, ntl, y2,
                                          stats + 256, n2);
    k_final<<<ewBlocks16, 256, 0, stream>>>(y2, gamma2, beta2, stats + 256,
                                            (float*)d_out, n2);
}